// Round 10
// baseline (374.454 us; speedup 1.0000x reference)
//
#include <hip/hip_runtime.h>
#include <hip/hip_bf16.h>
#include <hip/hip_cooperative_groups.h>
#include <math.h>

namespace cg = cooperative_groups;

#define H_DIM 288
#define NHEADS 18
#define HEAD_D 16
#define SEQ 2048
#define BATCH 2
#define M_TOT (BATCH*SEQ)       // 4096
#define XCNT (M_TOT*H_DIM)      // 1179648
#define WCNT (H_DIM*H_DIM)      // 82944
#define NUNITS 10368            // 36 bh x 288 (qp,chunk) split-K units
#define NQUNITS 2304            // 36 bh x 64 qp
#define NBLK 512                // cooperative grid: 2 blocks/CU guaranteed
#define NGW (NBLK*4)            // 2048 grid waves

typedef _Float16 f16_t;
typedef __attribute__((ext_vector_type(4))) _Float16 half4v;
typedef __attribute__((ext_vector_type(8))) _Float16 half8v;
typedef __attribute__((ext_vector_type(4))) float   float4v;

// ---------------------------------------------------------------------------
// Single cooperative kernel, 5 phases separated by grid.sync():
//  P0 cvt fp32->f16 (X + 4 weights)
//  P1 QKV MFMA GEMM + fused RoPE (Q pre-scaled 0.25*log2e), V -> tiled Vt
//  P2 flash attention split-K partials (bulk-loaded full chunks)
//  P3 partial reduction -> f16 O
//  P4 output projection MFMA -> fp32 d_out
// No LDS anywhere; <=~110 VGPR; zero launch gaps between phases.
// ---------------------------------------------------------------------------
__global__ __launch_bounds__(256, 2) void fused_attn(
    const float* __restrict__ X,
    const float* __restrict__ Wq, const float* __restrict__ Wk,
    const float* __restrict__ Wv, const float* __restrict__ Wo,
    float* __restrict__ out,
    f16_t* __restrict__ Xf, f16_t* __restrict__ Wf,
    f16_t* __restrict__ Q16, f16_t* __restrict__ K16, f16_t* __restrict__ Vt,
    f16_t* __restrict__ Of, float4* __restrict__ accbuf, float* __restrict__ lbuf)
{
    cg::grid_group grid = cg::this_grid();
    const int wave = threadIdx.x >> 6;
    const int lane = threadIdx.x & 63;
    const int n = lane & 15, quad = lane >> 4;
    const int gwave = blockIdx.x*4 + wave;

    // ---------------- P0: convert inputs to f16 ----------------
    {
        const int tid = blockIdx.x*256 + threadIdx.x;   // 131072 threads
        const int X4 = XCNT/4, W4 = WCNT/4;
        const int total4 = X4 + 4*W4;
        for (int i = tid; i < total4; i += NBLK*256) {
            const float* src; f16_t* dst; int off;
            if (i < X4) { src = X; dst = Xf; off = i; }
            else {
                int r = i - X4;
                int wz = r / W4; off = r - wz*W4;
                src = (wz==0) ? Wq : (wz==1) ? Wk : (wz==2) ? Wv : Wo;
                dst = Wf + (size_t)wz*WCNT;
            }
            float4 v = ((const float4*)src)[off];
            half4v h; h[0]=(f16_t)v.x; h[1]=(f16_t)v.y; h[2]=(f16_t)v.z; h[3]=(f16_t)v.w;
            ((half4v*)dst)[off] = h;
        }
    }
    grid.sync();

    // ---------------- P1: QKV GEMM + RoPE epilogue ----------------
    for (int u = gwave; u < 2304; u += NGW) {
        const int bx = u % 18;          // z*6 + n-block
        const int by = u / 18;          // m-block
        const int z  = bx/6;
        const int n0 = (bx - z*6)*48;
        const int m0 = by*32;
        const f16_t* W = Wf + (size_t)z*WCNT;

        float4v acc[2][3];
        #pragma unroll
        for (int mt = 0; mt < 2; mt++)
            #pragma unroll
            for (int nt = 0; nt < 3; nt++)
                acc[mt][nt] = (float4v){0.f,0.f,0.f,0.f};

        for (int k0 = 0; k0 < H_DIM; k0 += 32) {
            half8v a[2], b[3];
            #pragma unroll
            for (int mt = 0; mt < 2; mt++)
                a[mt] = *(const half8v*)(Xf + (size_t)(m0 + mt*16 + n)*H_DIM + k0 + quad*8);
            #pragma unroll
            for (int nt = 0; nt < 3; nt++)
                b[nt] = *(const half8v*)(W + (size_t)(n0 + nt*16 + n)*H_DIM + k0 + quad*8);
            #pragma unroll
            for (int mt = 0; mt < 2; mt++)
                #pragma unroll
                for (int nt = 0; nt < 3; nt++)
                    acc[mt][nt] = __builtin_amdgcn_mfma_f32_16x16x32_f16(a[mt], b[nt], acc[mt][nt], 0, 0, 0);
        }

        if (z < 2) {   // Q or K: RoPE
            f16_t* dst = (z == 0) ? Q16 : K16;
            const float invf = exp2f(-1.6609640474436813f * (float)(n & 7));
            #pragma unroll
            for (int mt = 0; mt < 2; mt++) {
                #pragma unroll
                for (int r = 0; r < 4; r++) {
                    int m = m0 + mt*16 + quad*4 + r;
                    int bb = m >> 11, s = m & (SEQ - 1);
                    float ang = (float)s * invf;
                    float c, sn;
                    sincosf(ang, &sn, &c);
                    #pragma unroll
                    for (int nt = 0; nt < 3; nt++) {
                        float own = acc[mt][nt][r];
                        float par = __shfl_xor(own, 8, 64);
                        float val = (n & 8) ? fmaf(own, c, par*sn) : fmaf(own, c, -par*sn);
                        if (z == 0) val *= 0.36067376022224085f;  // 0.25*log2(e)
                        int head = (n0 >> 4) + nt;
                        dst[((size_t)((bb*NHEADS + head)*SEQ) + s)*HEAD_D + n] = (f16_t)val;
                    }
                }
            }
        } else {       // V: transposed tiled store
            #pragma unroll
            for (int mt = 0; mt < 2; mt++)
                #pragma unroll
                for (int nt = 0; nt < 3; nt++)
                    #pragma unroll
                    for (int r = 0; r < 4; r++) {
                        int m = m0 + mt*16 + quad*4 + r;
                        int bb = m >> 11, s = m & (SEQ - 1);
                        int head = (n0 >> 4) + nt;
                        Vt[(size_t)(bb*NHEADS + head)*(SEQ*HEAD_D)
                           + (size_t)(s >> 4)*256 + n*16 + (s & 15)] = (f16_t)acc[mt][nt][r];
                    }
        }
    }
    grid.sync();

    // ---------------- P2: attention split-K partials ----------------
    for (int unit = gwave; unit < NUNITS; unit += NGW) {
        const int bh = unit / 288;
        const int rem = unit - bh*288;
        int g, t0;
        if      (rem < 8)   { g=0; t0=rem;     }
        else if (rem < 24)  { g=1; t0=rem-8;   }
        else if (rem < 48)  { g=2; t0=rem-24;  }
        else if (rem < 80)  { g=3; t0=rem-48;  }
        else if (rem < 120) { g=4; t0=rem-80;  }
        else if (rem < 168) { g=5; t0=rem-120; }
        else if (rem < 224) { g=6; t0=rem-168; }
        else                { g=7; t0=rem-224; }
        const int qd = t0 / (g+1);
        const int qp = 8*g + qd;
        const int chunk = t0 - qd*(g+1);
        const int q0 = qp*32;

        half4v qb0 = *(const half4v*)(Q16 + ((size_t)bh*SEQ + q0 + n)*HEAD_D + quad*4);
        half4v qb1 = *(const half4v*)(Q16 + ((size_t)bh*SEQ + q0 + 16 + n)*HEAD_D + quad*4);
        const f16_t* Kb = K16 + (size_t)bh * SEQ * HEAD_D;
        const f16_t* Vb = Vt  + (size_t)bh * SEQ * HEAD_D;
        const int loff = n*16 + quad*4;   // same lane offset for K rows and Vt tiles

        const float4v zero = {0.f, 0.f, 0.f, 0.f};
        float4v acc0 = zero, acc1 = zero;
        float l0 = 0.f, l1 = 0.f;

        const int lim0 = 2*qp, lim1 = 2*qp + 1;
        const int ktlo = chunk*16;
        const int kthi = min(ktlo + 15, lim1);

        if (ktlo + 15 < lim0) {
            // Bulk path: full 16-tile unmasked chunk; all 32 loads up-front.
            half4v KA[16], VA[16];
            #pragma unroll
            for (int i = 0; i < 16; i++) {
                KA[i] = *(const half4v*)(Kb + (size_t)(ktlo + i)*256 + loff);
                VA[i] = *(const half4v*)(Vb + (size_t)(ktlo + i)*256 + loff);
            }
            #pragma unroll
            for (int i = 0; i < 16; i++) {
                float4v s1 = __builtin_amdgcn_mfma_f32_16x16x16f16(KA[i], qb1, zero, 0, 0, 0);
                float4v s0 = __builtin_amdgcn_mfma_f32_16x16x16f16(KA[i], qb0, zero, 0, 0, 0);
                float p1[4], p0[4];
                #pragma unroll
                for (int r = 0; r < 4; r++) { p1[r] = __builtin_amdgcn_exp2f(s1[r]); p0[r] = __builtin_amdgcn_exp2f(s0[r]); }
                l1 += (p1[0]+p1[1]) + (p1[2]+p1[3]);
                l0 += (p0[0]+p0[1]) + (p0[2]+p0[3]);
                half4v pb1, pb0;
                #pragma unroll
                for (int r = 0; r < 4; r++) { pb1[r]=(f16_t)p1[r]; pb0[r]=(f16_t)p0[r]; }
                acc1 = __builtin_amdgcn_mfma_f32_16x16x16f16(VA[i], pb1, acc1, 0, 0, 0);
                acc0 = __builtin_amdgcn_mfma_f32_16x16x16f16(VA[i], pb0, acc0, 0, 0, 0);
            }
        } else {
            // Diagonal/partial chunk: per-tile loop with causal masks.
            int kt = ktlo;
            half4v ka = *(const half4v*)(Kb + (size_t)kt*256 + loff);
            half4v va = *(const half4v*)(Vb + (size_t)kt*256 + loff);
            for (; kt <= kthi; kt++) {
                half4v kan, van;
                if (kt < kthi) {
                    kan = *(const half4v*)(Kb + (size_t)(kt+1)*256 + loff);
                    van = *(const half4v*)(Vb + (size_t)(kt+1)*256 + loff);
                }
                {   // tile 1
                    float4v s = __builtin_amdgcn_mfma_f32_16x16x16f16(ka, qb1, zero, 0, 0, 0);
                    float p[4];
                    #pragma unroll
                    for (int r = 0; r < 4; r++) {
                        float e = __builtin_amdgcn_exp2f(s[r]);
                        p[r] = (kt == lim1 && quad*4 + r > n) ? 0.0f : e;
                    }
                    l1 += (p[0]+p[1]) + (p[2]+p[3]);
                    half4v pb;
                    #pragma unroll
                    for (int r = 0; r < 4; r++) pb[r]=(f16_t)p[r];
                    acc1 = __builtin_amdgcn_mfma_f32_16x16x16f16(va, pb, acc1, 0, 0, 0);
                }
                if (kt <= lim0) {   // tile 0
                    float4v s = __builtin_amdgcn_mfma_f32_16x16x16f16(ka, qb0, zero, 0, 0, 0);
                    float p[4];
                    #pragma unroll
                    for (int r = 0; r < 4; r++) {
                        float e = __builtin_amdgcn_exp2f(s[r]);
                        p[r] = (kt == lim0 && quad*4 + r > n) ? 0.0f : e;
                    }
                    l0 += (p[0]+p[1]) + (p[2]+p[3]);
                    half4v pb;
                    #pragma unroll
                    for (int r = 0; r < 4; r++) pb[r]=(f16_t)p[r];
                    acc0 = __builtin_amdgcn_mfma_f32_16x16x16f16(va, pb, acc0, 0, 0, 0);
                }
                ka = kan; va = van;
            }
        }

        float4 a0; a0.x=acc0[0]; a0.y=acc0[1]; a0.z=acc0[2]; a0.w=acc0[3];
        float4 a1; a1.x=acc1[0]; a1.y=acc1[1]; a1.z=acc1[2]; a1.w=acc1[3];
        accbuf[((size_t)unit*2 + 0)*64 + lane] = a0;
        accbuf[((size_t)unit*2 + 1)*64 + lane] = a1;
        lbuf[((size_t)unit*2 + 0)*64 + lane] = l0;
        lbuf[((size_t)unit*2 + 1)*64 + lane] = l1;
    }
    grid.sync();

    // ---------------- P3: reduce partials -> f16 O ----------------
    for (int wid = gwave; wid < NQUNITS; wid += NGW) {
        const int bh = wid >> 6, qp = wid & 63;
        const int b = bh / NHEADS, h = bh - b*NHEADS;
        const int g = qp >> 3, j = qp & 7;
        const int nch = g + 1;
        const int ubase = bh*288 + qp + 4*g*(g-1) + g*j;

        #pragma unroll
        for (int t = 0; t < 2; t++) {
            float4 a = {0.f, 0.f, 0.f, 0.f};
            float l = 0.f;
            for (int c = 0; c < nch; c++) {
                size_t idx = ((size_t)(ubase + c)*2 + t)*64 + lane;
                float4 v = accbuf[idx];
                a.x += v.x; a.y += v.y; a.z += v.z; a.w += v.w;
                l += lbuf[idx];
            }
            l += __shfl_xor(l, 16, 64);
            l += __shfl_xor(l, 32, 64);
            float inv = 1.0f / l;
            half4v o;
            o[0]=(f16_t)(a.x*inv); o[1]=(f16_t)(a.y*inv);
            o[2]=(f16_t)(a.z*inv); o[3]=(f16_t)(a.w*inv);
            *(half4v*)(Of + (size_t)(b*SEQ + qp*32 + t*16 + n)*H_DIM + h*HEAD_D + quad*4) = o;
        }
    }
    grid.sync();

    // ---------------- P4: output projection -> fp32 ----------------
    for (int u = gwave; u < 768; u += NGW) {
        const int n0 = (u % 6) * 48;
        const int m0 = (u / 6) * 32;
        const f16_t* Wo16 = Wf + 3*(size_t)WCNT;

        float4v acc[2][3];
        #pragma unroll
        for (int mt = 0; mt < 2; mt++)
            #pragma unroll
            for (int nt = 0; nt < 3; nt++)
                acc[mt][nt] = (float4v){0.f,0.f,0.f,0.f};

        for (int k0 = 0; k0 < H_DIM; k0 += 32) {
            half8v a[2], b[3];
            #pragma unroll
            for (int mt = 0; mt < 2; mt++)
                a[mt] = *(const half8v*)(Of + (size_t)(m0 + mt*16 + n)*H_DIM + k0 + quad*8);
            #pragma unroll
            for (int nt = 0; nt < 3; nt++)
                b[nt] = *(const half8v*)(Wo16 + (size_t)(n0 + nt*16 + n)*H_DIM + k0 + quad*8);
            #pragma unroll
            for (int mt = 0; mt < 2; mt++)
                #pragma unroll
                for (int nt = 0; nt < 3; nt++)
                    acc[mt][nt] = __builtin_amdgcn_mfma_f32_16x16x32_f16(a[mt], b[nt], acc[mt][nt], 0, 0, 0);
        }
        #pragma unroll
        for (int mt = 0; mt < 2; mt++)
            #pragma unroll
            for (int nt = 0; nt < 3; nt++)
                #pragma unroll
                for (int r = 0; r < 4; r++) {
                    int m = m0 + mt*16 + quad*4 + r;
                    out[(size_t)m*H_DIM + n0 + nt*16 + n] = acc[mt][nt][r];
                }
    }
}

// ---------------------------------------------------------------------------
extern "C" void kernel_launch(void* const* d_in, const int* in_sizes, int n_in,
                              void* d_out, int out_size, void* d_ws, size_t ws_size,
                              hipStream_t stream)
{
    const float* Xh = (const float*)d_in[0];
    const float* Wq = (const float*)d_in[1];
    const float* Wk = (const float*)d_in[2];
    const float* Wv = (const float*)d_in[3];
    const float* Wo = (const float*)d_in[4];
    float* out = (float*)d_out;

    f16_t* Xf  = (f16_t*)d_ws;                  // XCNT
    f16_t* Wf  = Xf + XCNT;                     // 4*WCNT
    f16_t* Q16 = Wf + 4*(size_t)WCNT;           // XCNT
    f16_t* K16 = Q16 + XCNT;                    // XCNT
    f16_t* Vt  = K16 + XCNT;                    // XCNT
    f16_t* Of  = Vt + XCNT;                     // XCNT
    float4* accbuf = (float4*)(Of + XCNT);      // NUNITS*2*64 float4
    float*  lbuf   = (float*)(accbuf + (size_t)NUNITS*2*64);

    void* args[] = {
        (void*)&Xh, (void*)&Wq, (void*)&Wk, (void*)&Wv, (void*)&Wo,
        (void*)&out, (void*)&Xf, (void*)&Wf, (void*)&Q16, (void*)&K16,
        (void*)&Vt, (void*)&Of, (void*)&accbuf, (void*)&lbuf
    };
    hipLaunchCooperativeKernel((const void*)fused_attn, dim3(NBLK), dim3(256),
                               args, 0, stream);
}

// Round 11
// 165.001 us; speedup vs baseline: 2.2694x; 2.2694x over previous
//
#include <hip/hip_runtime.h>
#include <hip/hip_bf16.h>
#include <math.h>

#define H_DIM 288
#define NHEADS 18
#define HEAD_D 16
#define SEQ 2048
#define BATCH 2
#define M_TOT (BATCH*SEQ)       // 4096
#define XCNT (M_TOT*H_DIM)      // 1179648
#define WCNT (H_DIM*H_DIM)      // 82944
#define NUNITS 10368            // 36 bh x 288 (qp,chunk) split-K units

typedef _Float16 f16_t;
typedef __attribute__((ext_vector_type(4))) _Float16 half4v;
typedef __attribute__((ext_vector_type(8))) _Float16 half8v;
typedef __attribute__((ext_vector_type(4))) float   float4v;

__device__ __forceinline__ half8v f32x8_to_h8(float4 a, float4 b) {
    half8v h;
    h[0]=(f16_t)a.x; h[1]=(f16_t)a.y; h[2]=(f16_t)a.z; h[3]=(f16_t)a.w;
    h[4]=(f16_t)b.x; h[5]=(f16_t)b.y; h[6]=(f16_t)b.z; h[7]=(f16_t)b.w;
    return h;
}

// ---------------------------------------------------------------------------
// K1: QKV projection via MFMA 16x16x32 f16, fp32 inputs converted in-register
// (no cvt pass). One wave/block, tile M=32 x N=48, grid (18,128).
// Epilogue: Q,K -> RoPE -> f16 [b,h,s,d]; Q pre-scaled 0.25*log2(e) so
// attention softmax uses raw exp2. V -> f16 tiled Vt[bh][s>>4][d][s&15].
// ---------------------------------------------------------------------------
__global__ __launch_bounds__(64) void qkv_mfma(
    const float* __restrict__ X,
    const float* __restrict__ Wq, const float* __restrict__ Wk, const float* __restrict__ Wv,
    f16_t* __restrict__ Q16, f16_t* __restrict__ K16, f16_t* __restrict__ Vt)
{
    const int bx = blockIdx.x;          // 0..17
    const int z  = bx/6;
    const int n0 = (bx - z*6)*48;
    const int m0 = blockIdx.y*32;
    const int lane = threadIdx.x & 63;
    const int n = lane & 15, quad = lane >> 4;

    const float* W = (z == 0) ? Wq : (z == 1) ? Wk : Wv;

    float4v acc[2][3];
    #pragma unroll
    for (int mt = 0; mt < 2; mt++)
        #pragma unroll
        for (int nt = 0; nt < 3; nt++)
            acc[mt][nt] = (float4v){0.f,0.f,0.f,0.f};

    for (int k0 = 0; k0 < H_DIM; k0 += 32) {
        half8v a[2], b[3];
        #pragma unroll
        for (int mt = 0; mt < 2; mt++) {
            const float4* p = (const float4*)(X + (size_t)(m0 + mt*16 + n)*H_DIM + k0 + quad*8);
            a[mt] = f32x8_to_h8(p[0], p[1]);
        }
        #pragma unroll
        for (int nt = 0; nt < 3; nt++) {
            const float4* p = (const float4*)(W + (size_t)(n0 + nt*16 + n)*H_DIM + k0 + quad*8);
            b[nt] = f32x8_to_h8(p[0], p[1]);
        }
        #pragma unroll
        for (int mt = 0; mt < 2; mt++)
            #pragma unroll
            for (int nt = 0; nt < 3; nt++)
                acc[mt][nt] = __builtin_amdgcn_mfma_f32_16x16x32_f16(a[mt], b[nt], acc[mt][nt], 0, 0, 0);
    }

    if (z < 2) {   // Q or K: RoPE epilogue
        f16_t* dst = (z == 0) ? Q16 : K16;
        const float invf = exp2f(-1.6609640474436813f * (float)(n & 7));
        #pragma unroll
        for (int mt = 0; mt < 2; mt++) {
            #pragma unroll
            for (int r = 0; r < 4; r++) {
                int m = m0 + mt*16 + quad*4 + r;
                int bb = m >> 11, s = m & (SEQ - 1);
                float ang = (float)s * invf;
                float c, sn;
                sincosf(ang, &sn, &c);
                #pragma unroll
                for (int nt = 0; nt < 3; nt++) {
                    float own = acc[mt][nt][r];
                    float par = __shfl_xor(own, 8, 64);
                    float val = (n & 8) ? fmaf(own, c, par*sn) : fmaf(own, c, -par*sn);
                    if (z == 0) val *= 0.36067376022224085f;  // 0.25 * log2(e)
                    int head = (n0 >> 4) + nt;
                    dst[((size_t)((bb*NHEADS + head)*SEQ) + s)*HEAD_D + n] = (f16_t)val;
                }
            }
        }
    } else {       // V: transposed tiled store
        #pragma unroll
        for (int mt = 0; mt < 2; mt++)
            #pragma unroll
            for (int nt = 0; nt < 3; nt++)
                #pragma unroll
                for (int r = 0; r < 4; r++) {
                    int m = m0 + mt*16 + quad*4 + r;
                    int bb = m >> 11, s = m & (SEQ - 1);
                    int head = (n0 >> 4) + nt;
                    Vt[(size_t)(bb*NHEADS + head)*(SEQ*HEAD_D)
                       + (size_t)(s >> 4)*256 + n*16 + (s & 15)] = (f16_t)acc[mt][nt][r];
                }
    }
}

// ---------------------------------------------------------------------------
// K2: flash attention split-K partials (R9-proven) + bulk path for full
// unmasked 16-tile chunks (all 32 K/V loads issued up-front; validated R10).
// One wave per unit (bh, qp, chunk); partials to ws. No LDS.
// ---------------------------------------------------------------------------
__global__ __launch_bounds__(256) void attn_part(
    const f16_t* __restrict__ Q16, const f16_t* __restrict__ K16,
    const f16_t* __restrict__ Vt,
    float4* __restrict__ accbuf, float* __restrict__ lbuf)
{
    const int unit = blockIdx.x*4 + (threadIdx.x >> 6);   // 0..10367
    const int lane = threadIdx.x & 63;
    const int n = lane & 15, quad = lane >> 4;

    const int bh = unit / 288;
    const int rem = unit - bh*288;
    int g, t0;
    if      (rem < 8)   { g=0; t0=rem;     }
    else if (rem < 24)  { g=1; t0=rem-8;   }
    else if (rem < 48)  { g=2; t0=rem-24;  }
    else if (rem < 80)  { g=3; t0=rem-48;  }
    else if (rem < 120) { g=4; t0=rem-80;  }
    else if (rem < 168) { g=5; t0=rem-120; }
    else if (rem < 224) { g=6; t0=rem-168; }
    else                { g=7; t0=rem-224; }
    const int qd = t0 / (g+1);
    const int qp = 8*g + qd;
    const int chunk = t0 - qd*(g+1);
    const int q0 = qp*32;

    half4v qb0 = *(const half4v*)(Q16 + ((size_t)bh*SEQ + q0 + n)*HEAD_D + quad*4);
    half4v qb1 = *(const half4v*)(Q16 + ((size_t)bh*SEQ + q0 + 16 + n)*HEAD_D + quad*4);
    const f16_t* Kb = K16 + (size_t)bh * SEQ * HEAD_D;
    const f16_t* Vb = Vt  + (size_t)bh * SEQ * HEAD_D;
    const int loff = n*16 + quad*4;

    const float4v zero = {0.f, 0.f, 0.f, 0.f};
    float4v acc0 = zero, acc1 = zero;
    float l0 = 0.f, l1 = 0.f;

    const int lim0 = 2*qp, lim1 = 2*qp + 1;
    const int ktlo = chunk*16;
    const int kthi = min(ktlo + 15, lim1);

    if (ktlo + 15 < lim0) {
        half4v KA[16], VA[16];
        #pragma unroll
        for (int i = 0; i < 16; i++) {
            KA[i] = *(const half4v*)(Kb + (size_t)(ktlo + i)*256 + loff);
            VA[i] = *(const half4v*)(Vb + (size_t)(ktlo + i)*256 + loff);
        }
        #pragma unroll
        for (int i = 0; i < 16; i++) {
            float4v s1 = __builtin_amdgcn_mfma_f32_16x16x16f16(KA[i], qb1, zero, 0, 0, 0);
            float4v s0 = __builtin_amdgcn_mfma_f32_16x16x16f16(KA[i], qb0, zero, 0, 0, 0);
            float p1[4], p0[4];
            #pragma unroll
            for (int r = 0; r < 4; r++) { p1[r] = __builtin_amdgcn_exp2f(s1[r]); p0[r] = __builtin_amdgcn_exp2f(s0[r]); }
            l1 += (p1[0]+p1[1]) + (p1[2]+p1[3]);
            l0 += (p0[0]+p0[1]) + (p0[2]+p0[3]);
            half4v pb1, pb0;
            #pragma unroll
            for (int r = 0; r < 4; r++) { pb1[r]=(f16_t)p1[r]; pb0[r]=(f16_t)p0[r]; }
            acc1 = __builtin_amdgcn_mfma_f32_16x16x16f16(VA[i], pb1, acc1, 0, 0, 0);
            acc0 = __builtin_amdgcn_mfma_f32_16x16x16f16(VA[i], pb0, acc0, 0, 0, 0);
        }
    } else {
        int kt = ktlo;
        half4v ka = *(const half4v*)(Kb + (size_t)kt*256 + loff);
        half4v va = *(const half4v*)(Vb + (size_t)kt*256 + loff);
        for (; kt <= kthi; kt++) {
            half4v kan, van;
            if (kt < kthi) {
                kan = *(const half4v*)(Kb + (size_t)(kt+1)*256 + loff);
                van = *(const half4v*)(Vb + (size_t)(kt+1)*256 + loff);
            }
            {   // tile 1
                float4v s = __builtin_amdgcn_mfma_f32_16x16x16f16(ka, qb1, zero, 0, 0, 0);
                float p[4];
                #pragma unroll
                for (int r = 0; r < 4; r++) {
                    float e = __builtin_amdgcn_exp2f(s[r]);
                    p[r] = (kt == lim1 && quad*4 + r > n) ? 0.0f : e;
                }
                l1 += (p[0]+p[1]) + (p[2]+p[3]);
                half4v pb;
                #pragma unroll
                for (int r = 0; r < 4; r++) pb[r]=(f16_t)p[r];
                acc1 = __builtin_amdgcn_mfma_f32_16x16x16f16(va, pb, acc1, 0, 0, 0);
            }
            if (kt <= lim0) {   // tile 0
                float4v s = __builtin_amdgcn_mfma_f32_16x16x16f16(ka, qb0, zero, 0, 0, 0);
                float p[4];
                #pragma unroll
                for (int r = 0; r < 4; r++) {
                    float e = __builtin_amdgcn_exp2f(s[r]);
                    p[r] = (kt == lim0 && quad*4 + r > n) ? 0.0f : e;
                }
                l0 += (p[0]+p[1]) + (p[2]+p[3]);
                half4v pb;
                #pragma unroll
                for (int r = 0; r < 4; r++) pb[r]=(f16_t)p[r];
                acc0 = __builtin_amdgcn_mfma_f32_16x16x16f16(va, pb, acc0, 0, 0, 0);
            }
            ka = kan; va = van;
        }
    }

    float4 a0; a0.x=acc0[0]; a0.y=acc0[1]; a0.z=acc0[2]; a0.w=acc0[3];
    float4 a1; a1.x=acc1[0]; a1.y=acc1[1]; a1.z=acc1[2]; a1.w=acc1[3];
    accbuf[((size_t)unit*2 + 0)*64 + lane] = a0;
    accbuf[((size_t)unit*2 + 1)*64 + lane] = a1;
    lbuf[((size_t)unit*2 + 0)*64 + lane] = l0;
    lbuf[((size_t)unit*2 + 1)*64 + lane] = l1;
}

// ---------------------------------------------------------------------------
// K3: fused partial-reduction + output projection.
// One block (4 waves) per (b, qp): reduce 18 heads' split-K partials for 32
// queries into LDS O-tile [32][288] (stride 296 f16 -> 2-way banks, free),
// barrier, then MFMA GEMM vs Wo (fp32, in-register cvt), fp32 store.
// ---------------------------------------------------------------------------
#define OLSTR 296
__global__ __launch_bounds__(256) void red_out(
    const float4* __restrict__ accbuf, const float* __restrict__ lbuf,
    const float* __restrict__ Wo, float* __restrict__ C)
{
    const int bq = blockIdx.x;            // 0..127 = b*64 + qp
    const int b = bq >> 6, qp = bq & 63;
    const int wave = threadIdx.x >> 6;
    const int lane = threadIdx.x & 63;
    const int n = lane & 15, quad = lane >> 4;
    const int g = qp >> 3, j = qp & 7;
    const int nch = g + 1;
    const int m0 = b*SEQ + qp*32;

    __shared__ f16_t Ol[32 * OLSTR];      // 18944 B

    // ---- reduction: 36 (h,t) units, 9 per wave ----
    for (int u = wave*9; u < wave*9 + 9; u++) {
        const int h = u >> 1, t = u & 1;
        const int bh = b*NHEADS + h;
        const int ubase = bh*288 + qp + 4*g*(g-1) + g*j;
        float4 a = {0.f, 0.f, 0.f, 0.f};
        float l = 0.f;
        for (int c = 0; c < nch; c++) {
            size_t idx = ((size_t)(ubase + c)*2 + t)*64 + lane;
            float4 v = accbuf[idx];
            a.x += v.x; a.y += v.y; a.z += v.z; a.w += v.w;
            l += lbuf[idx];
        }
        l += __shfl_xor(l, 16, 64);
        l += __shfl_xor(l, 32, 64);
        float inv = 1.0f / l;
        half4v o;
        o[0]=(f16_t)(a.x*inv); o[1]=(f16_t)(a.y*inv);
        o[2]=(f16_t)(a.z*inv); o[3]=(f16_t)(a.w*inv);
        *(half4v*)(&Ol[(t*16 + n)*OLSTR + h*16 + quad*4]) = o;
    }
    __syncthreads();

    // ---- GEMM: out[m0+..][*] = Ol @ Wo^T ----
    // n-tiles 0..17 split: wave w -> {w, w+4, w+8, w+12} (+{16+w} for w<2)
    const int nnt = (wave < 2) ? 5 : 4;
    float4v acc[2][5];
    #pragma unroll
    for (int mt = 0; mt < 2; mt++)
        #pragma unroll
        for (int i = 0; i < 5; i++)
            acc[mt][i] = (float4v){0.f,0.f,0.f,0.f};

    for (int k0 = 0; k0 < H_DIM; k0 += 32) {
        half8v a[2];
        #pragma unroll
        for (int mt = 0; mt < 2; mt++)
            a[mt] = *(const half8v*)(&Ol[(mt*16 + n)*OLSTR + k0 + quad*8]);
        for (int i = 0; i < nnt; i++) {
            const int nt = (i < 4) ? (wave + 4*i) : (16 + wave);
            const float4* p = (const float4*)(Wo + (size_t)(nt*16 + n)*H_DIM + k0 + quad*8);
            half8v bfrag = f32x8_to_h8(p[0], p[1]);
            #pragma unroll
            for (int mt = 0; mt < 2; mt++)
                acc[mt][i] = __builtin_amdgcn_mfma_f32_16x16x32_f16(a[mt], bfrag, acc[mt][i], 0, 0, 0);
        }
    }
    for (int i = 0; i < nnt; i++) {
        const int nt = (i < 4) ? (wave + 4*i) : (16 + wave);
        #pragma unroll
        for (int mt = 0; mt < 2; mt++)
            #pragma unroll
            for (int r = 0; r < 4; r++) {
                int m = m0 + mt*16 + quad*4 + r;
                C[(size_t)m*H_DIM + nt*16 + n] = acc[mt][i][r];
            }
    }
}

// ---------------------------------------------------------------------------
extern "C" void kernel_launch(void* const* d_in, const int* in_sizes, int n_in,
                              void* d_out, int out_size, void* d_ws, size_t ws_size,
                              hipStream_t stream)
{
    const float* Xh = (const float*)d_in[0];
    const float* Wq = (const float*)d_in[1];
    const float* Wk = (const float*)d_in[2];
    const float* Wv = (const float*)d_in[3];
    const float* Wo = (const float*)d_in[4];
    float* out = (float*)d_out;

    f16_t* Q16 = (f16_t*)d_ws;                  // XCNT
    f16_t* K16 = Q16 + XCNT;                    // XCNT
    f16_t* Vt  = K16 + XCNT;                    // XCNT
    float4* accbuf = (float4*)(Vt + XCNT);      // NUNITS*2*64 float4
    float*  lbuf   = (float*)(accbuf + (size_t)NUNITS*2*64);

    qkv_mfma<<<dim3(18, 128), 64, 0, stream>>>(Xh, Wq, Wk, Wv, Q16, K16, Vt);
    attn_part<<<dim3(NUNITS/4), 256, 0, stream>>>(Q16, K16, Vt, accbuf, lbuf);
    red_out<<<dim3(128), 256, 0, stream>>>(accbuf, lbuf, Wo, out);
}

// Round 13
// 112.684 us; speedup vs baseline: 3.3230x; 1.4643x over previous
//
#include <hip/hip_runtime.h>
#include <hip/hip_bf16.h>
#include <math.h>

#define H_DIM 288
#define NHEADS 18
#define HEAD_D 16
#define SEQ 2048
#define BATCH 2
#define M_TOT (BATCH*SEQ)       // 4096
#define XCNT (M_TOT*H_DIM)      // 1179648
#define WCNT (H_DIM*H_DIM)      // 82944
#define NUNITS 10368            // 36 bh x 288 (qp,chunk) split-K units
#define NQUNITS 2304            // 36 bh x 64 qp

typedef _Float16 f16_t;
typedef __attribute__((ext_vector_type(2))) _Float16 half2v;
typedef __attribute__((ext_vector_type(4))) _Float16 half4v;
typedef __attribute__((ext_vector_type(8))) _Float16 half8v;
typedef __attribute__((ext_vector_type(4))) float   float4v;

// ---------------------------------------------------------------------------
// K0: fp32 -> f16 convert: X (4096x288) and the four 288x288 weights.
// ---------------------------------------------------------------------------
__global__ __launch_bounds__(256) void cvt_f16(
    const float* __restrict__ X,
    const float* __restrict__ Wq, const float* __restrict__ Wk,
    const float* __restrict__ Wv, const float* __restrict__ Wo,
    f16_t* __restrict__ Xf, f16_t* __restrict__ Wf)
{
    int idx = blockIdx.x * 256 + threadIdx.x;
    const int X4 = XCNT/4, W4 = WCNT/4;
    if (idx >= X4 + 4*W4) return;
    const float* src; f16_t* dst; int off;
    if (idx < X4) { src = X; dst = Xf; off = idx; }
    else {
        int r = idx - X4;
        int wz = r / W4; off = r - wz*W4;
        src = (wz==0) ? Wq : (wz==1) ? Wk : (wz==2) ? Wv : Wo;
        dst = Wf + (size_t)wz*WCNT;
    }
    float4 v = ((const float4*)src)[off];
    half4v h; h[0]=(f16_t)v.x; h[1]=(f16_t)v.y; h[2]=(f16_t)v.z; h[3]=(f16_t)v.w;
    ((half4v*)dst)[off] = h;
}

// ---------------------------------------------------------------------------
// K1: QKV projection via MFMA 16x16x32 f16 (R9-proven tiling). One wave per
// block, tile M=32 x N=48, grid (18,128).
// Epilogue: Q,K -> RoPE -> f16 [b,h,s,d]; Q pre-scaled 0.25*log2(e) so the
// attention softmax can use raw exp2.
// RoPE sin/cos via HW v_sin/v_cos in REVOLUTIONS with explicit fract range
// reduction (replaces libm sincosf's slow large-arg path; err ~1e-4 rad).
// V -> f16 tiled Vt[bh][s>>4][d][s&15].
// ---------------------------------------------------------------------------
__global__ __launch_bounds__(64) void qkv_mfma(
    const f16_t* __restrict__ Xf, const f16_t* __restrict__ Wf,
    f16_t* __restrict__ Q16, f16_t* __restrict__ K16, f16_t* __restrict__ Vt)
{
    const int bx = blockIdx.x;          // 0..17
    const int z  = bx/6;
    const int n0 = (bx - z*6)*48;
    const int m0 = blockIdx.y*32;
    const int lane = threadIdx.x & 63;
    const int n = lane & 15, quad = lane >> 4;

    const f16_t* W = Wf + (size_t)z*WCNT;

    float4v acc[2][3];
    #pragma unroll
    for (int mt = 0; mt < 2; mt++)
        #pragma unroll
        for (int nt = 0; nt < 3; nt++)
            acc[mt][nt] = (float4v){0.f,0.f,0.f,0.f};

    for (int k0 = 0; k0 < H_DIM; k0 += 32) {
        half8v a[2], b[3];
        #pragma unroll
        for (int mt = 0; mt < 2; mt++)
            a[mt] = *(const half8v*)(Xf + (size_t)(m0 + mt*16 + n)*H_DIM + k0 + quad*8);
        #pragma unroll
        for (int nt = 0; nt < 3; nt++)
            b[nt] = *(const half8v*)(W + (size_t)(n0 + nt*16 + n)*H_DIM + k0 + quad*8);
        #pragma unroll
        for (int mt = 0; mt < 2; mt++)
            #pragma unroll
            for (int nt = 0; nt < 3; nt++)
                acc[mt][nt] = __builtin_amdgcn_mfma_f32_16x16x32_f16(a[mt], b[nt], acc[mt][nt], 0, 0, 0);
    }

    if (z < 2) {   // Q or K: RoPE epilogue
        f16_t* dst = (z == 0) ? Q16 : K16;
        // invf in revolutions: theta^{-(d%8)/8} / (2*pi)
        const float invf_rev = exp2f(-1.6609640474436813f * (float)(n & 7))
                             * 0.15915494309189535f;
        #pragma unroll
        for (int mt = 0; mt < 2; mt++) {
            #pragma unroll
            for (int r = 0; r < 4; r++) {
                int m = m0 + mt*16 + quad*4 + r;
                int bb = m >> 11, s = m & (SEQ - 1);
                float rev = (float)s * invf_rev;
                float fr = rev - floorf(rev);
                float sn = __builtin_amdgcn_sinf(fr);   // sin(2*pi*fr)
                float c  = __builtin_amdgcn_cosf(fr);
                #pragma unroll
                for (int nt = 0; nt < 3; nt++) {
                    float own = acc[mt][nt][r];
                    float par = __shfl_xor(own, 8, 64);
                    float val = (n & 8) ? fmaf(own, c, par*sn) : fmaf(own, c, -par*sn);
                    if (z == 0) val *= 0.36067376022224085f;  // 0.25 * log2(e)
                    int head = (n0 >> 4) + nt;
                    dst[((size_t)((bb*NHEADS + head)*SEQ) + s)*HEAD_D + n] = (f16_t)val;
                }
            }
        }
    } else {       // V: transposed tiled store
        #pragma unroll
        for (int mt = 0; mt < 2; mt++)
            #pragma unroll
            for (int nt = 0; nt < 3; nt++)
                #pragma unroll
                for (int r = 0; r < 4; r++) {
                    int m = m0 + mt*16 + quad*4 + r;
                    int bb = m >> 11, s = m & (SEQ - 1);
                    int head = (n0 >> 4) + nt;
                    Vt[(size_t)(bb*NHEADS + head)*(SEQ*HEAD_D)
                       + (size_t)(s >> 4)*256 + n*16 + (s & 15)] = (f16_t)acc[mt][nt][r];
                }
    }
}

__device__ __forceinline__ half4v pack4(const float p[4]) {
    half2v ab = __builtin_bit_cast(half2v, __builtin_amdgcn_cvt_pkrtz(p[0], p[1]));
    half2v cd = __builtin_bit_cast(half2v, __builtin_amdgcn_cvt_pkrtz(p[2], p[3]));
    half4v o; o[0]=ab[0]; o[1]=ab[1]; o[2]=cd[0]; o[3]=cd[1];
    return o;
}

// ---------------------------------------------------------------------------
// K2: flash attention split-K partials (R9-proven) + bulk path for full
// unmasked 16-tile chunks (all 32 K/V loads up-front; validated R10/R11).
// One wave per unit (bh, qp, chunk); partials to ws. No LDS.
// ---------------------------------------------------------------------------
__global__ __launch_bounds__(256) void attn_part(
    const f16_t* __restrict__ Q16, const f16_t* __restrict__ K16,
    const f16_t* __restrict__ Vt,
    float4* __restrict__ accbuf, float* __restrict__ lbuf)
{
    const int unit = blockIdx.x*4 + (threadIdx.x >> 6);   // 0..10367
    const int lane = threadIdx.x & 63;
    const int n = lane & 15, quad = lane >> 4;

    const int bh = unit / 288;
    const int rem = unit - bh*288;
    int g, t0;
    if      (rem < 8)   { g=0; t0=rem;     }
    else if (rem < 24)  { g=1; t0=rem-8;   }
    else if (rem < 48)  { g=2; t0=rem-24;  }
    else if (rem < 80)  { g=3; t0=rem-48;  }
    else if (rem < 120) { g=4; t0=rem-80;  }
    else if (rem < 168) { g=5; t0=rem-120; }
    else if (rem < 224) { g=6; t0=rem-168; }
    else                { g=7; t0=rem-224; }
    const int qd = t0 / (g+1);
    const int qp = 8*g + qd;
    const int chunk = t0 - qd*(g+1);
    const int q0 = qp*32;

    half4v qb0 = *(const half4v*)(Q16 + ((size_t)bh*SEQ + q0 + n)*HEAD_D + quad*4);
    half4v qb1 = *(const half4v*)(Q16 + ((size_t)bh*SEQ + q0 + 16 + n)*HEAD_D + quad*4);
    const f16_t* Kb = K16 + (size_t)bh * SEQ * HEAD_D;
    const f16_t* Vb = Vt  + (size_t)bh * SEQ * HEAD_D;
    const int loff = n*16 + quad*4;

    const float4v zero = {0.f, 0.f, 0.f, 0.f};
    float4v acc0 = zero, acc1 = zero;
    float l0 = 0.f, l1 = 0.f;

    const int lim0 = 2*qp, lim1 = 2*qp + 1;
    const int ktlo = chunk*16;
    const int kthi = min(ktlo + 15, lim1);

    if (ktlo + 15 < lim0) {
        half4v KA[16], VA[16];
        #pragma unroll
        for (int i = 0; i < 16; i++) {
            KA[i] = *(const half4v*)(Kb + (size_t)(ktlo + i)*256 + loff);
            VA[i] = *(const half4v*)(Vb + (size_t)(ktlo + i)*256 + loff);
        }
        #pragma unroll
        for (int i = 0; i < 16; i++) {
            float4v s1 = __builtin_amdgcn_mfma_f32_16x16x16f16(KA[i], qb1, zero, 0, 0, 0);
            float4v s0 = __builtin_amdgcn_mfma_f32_16x16x16f16(KA[i], qb0, zero, 0, 0, 0);
            float p1[4], p0[4];
            #pragma unroll
            for (int r = 0; r < 4; r++) { p1[r] = __builtin_amdgcn_exp2f(s1[r]); p0[r] = __builtin_amdgcn_exp2f(s0[r]); }
            l1 += (p1[0]+p1[1]) + (p1[2]+p1[3]);
            l0 += (p0[0]+p0[1]) + (p0[2]+p0[3]);
            acc1 = __builtin_amdgcn_mfma_f32_16x16x16f16(VA[i], pack4(p1), acc1, 0, 0, 0);
            acc0 = __builtin_amdgcn_mfma_f32_16x16x16f16(VA[i], pack4(p0), acc0, 0, 0, 0);
        }
    } else {
        int kt = ktlo;
        half4v ka = *(const half4v*)(Kb + (size_t)kt*256 + loff);
        half4v va = *(const half4v*)(Vb + (size_t)kt*256 + loff);
        for (; kt <= kthi; kt++) {
            half4v kan, van;
            if (kt < kthi) {
                kan = *(const half4v*)(Kb + (size_t)(kt+1)*256 + loff);
                van = *(const half4v*)(Vb + (size_t)(kt+1)*256 + loff);
            }
            {   // tile 1
                float4v s = __builtin_amdgcn_mfma_f32_16x16x16f16(ka, qb1, zero, 0, 0, 0);
                float p[4];
                #pragma unroll
                for (int r = 0; r < 4; r++) {
                    float e = __builtin_amdgcn_exp2f(s[r]);
                    p[r] = (kt == lim1 && quad*4 + r > n) ? 0.0f : e;
                }
                l1 += (p[0]+p[1]) + (p[2]+p[3]);
                acc1 = __builtin_amdgcn_mfma_f32_16x16x16f16(va, pack4(p), acc1, 0, 0, 0);
            }
            if (kt <= lim0) {   // tile 0
                float4v s = __builtin_amdgcn_mfma_f32_16x16x16f16(ka, qb0, zero, 0, 0, 0);
                float p[4];
                #pragma unroll
                for (int r = 0; r < 4; r++) {
                    float e = __builtin_amdgcn_exp2f(s[r]);
                    p[r] = (kt == lim0 && quad*4 + r > n) ? 0.0f : e;
                }
                l0 += (p[0]+p[1]) + (p[2]+p[3]);
                acc0 = __builtin_amdgcn_mfma_f32_16x16x16f16(va, pack4(p), acc0, 0, 0, 0);
            }
            ka = kan; va = van;
        }
    }

    float4 a0; a0.x=acc0[0]; a0.y=acc0[1]; a0.z=acc0[2]; a0.w=acc0[3];
    float4 a1; a1.x=acc1[0]; a1.y=acc1[1]; a1.z=acc1[2]; a1.w=acc1[3];
    accbuf[((size_t)unit*2 + 0)*64 + lane] = a0;
    accbuf[((size_t)unit*2 + 1)*64 + lane] = a1;
    lbuf[((size_t)unit*2 + 0)*64 + lane] = l0;
    lbuf[((size_t)unit*2 + 1)*64 + lane] = l1;
}

// ---------------------------------------------------------------------------
// K3: reduction: one wave per (bh, qp) sums <=8 chunk partials, normalizes,
// writes f16 O. (R9-proven; 576 blocks.)
// ---------------------------------------------------------------------------
__global__ __launch_bounds__(256) void attn_red(
    const float4* __restrict__ accbuf, const float* __restrict__ lbuf,
    f16_t* __restrict__ Of)
{
    const int wid = blockIdx.x*4 + (threadIdx.x >> 6);    // 0..2303
    const int lane = threadIdx.x & 63;
    const int n = lane & 15, quad = lane >> 4;
    const int bh = wid >> 6, qp = wid & 63;
    const int b = bh / NHEADS, h = bh - b*NHEADS;
    const int g = qp >> 3, j = qp & 7;
    const int nch = g + 1;
    const int ubase = bh*288 + qp + 4*g*(g-1) + g*j;

    #pragma unroll
    for (int t = 0; t < 2; t++) {
        float4 a = {0.f, 0.f, 0.f, 0.f};
        float l = 0.f;
        for (int c = 0; c < nch; c++) {
            size_t idx = ((size_t)(ubase + c)*2 + t)*64 + lane;
            float4 v = accbuf[idx];
            a.x += v.x; a.y += v.y; a.z += v.z; a.w += v.w;
            l += lbuf[idx];
        }
        l += __shfl_xor(l, 16, 64);
        l += __shfl_xor(l, 32, 64);
        float inv = 1.0f / l;
        half4v o;
        o[0]=(f16_t)(a.x*inv); o[1]=(f16_t)(a.y*inv);
        o[2]=(f16_t)(a.z*inv); o[3]=(f16_t)(a.w*inv);
        *(half4v*)(Of + (size_t)(b*SEQ + qp*32 + t*16 + n)*H_DIM + h*HEAD_D + quad*4) = o;
    }
}

// ---------------------------------------------------------------------------
// K4: output projection via MFMA (R9-proven). Tile M=32 x N=48, grid (6,128).
// ---------------------------------------------------------------------------
__global__ __launch_bounds__(64) void out_mfma(
    const f16_t* __restrict__ Of, const f16_t* __restrict__ Wo16,
    float* __restrict__ C)
{
    const int n0 = blockIdx.x * 48;
    const int m0 = blockIdx.y * 32;
    const int lane = threadIdx.x & 63;
    const int n = lane & 15, quad = lane >> 4;

    float4v acc[2][3];
    #pragma unroll
    for (int mt = 0; mt < 2; mt++)
        #pragma unroll
        for (int nt = 0; nt < 3; nt++)
            acc[mt][nt] = (float4v){0.f,0.f,0.f,0.f};

    for (int k0 = 0; k0 < H_DIM; k0 += 32) {
        half8v a[2], b[3];
        #pragma unroll
        for (int mt = 0; mt < 2; mt++)
            a[mt] = *(const half8v*)(Of + (size_t)(m0 + mt*16 + n)*H_DIM + k0 + quad*8);
        #pragma unroll
        for (int nt = 0; nt < 3; nt++)
            b[nt] = *(const half8v*)(Wo16 + (size_t)(n0 + nt*16 + n)*H_DIM + k0 + quad*8);
        #pragma unroll
        for (int mt = 0; mt < 2; mt++)
            #pragma unroll
            for (int nt = 0; nt < 3; nt++)
                acc[mt][nt] = __builtin_amdgcn_mfma_f32_16x16x32_f16(a[mt], b[nt], acc[mt][nt], 0, 0, 0);
    }
    #pragma unroll
    for (int mt = 0; mt < 2; mt++)
        #pragma unroll
        for (int nt = 0; nt < 3; nt++)
            #pragma unroll
            for (int r = 0; r < 4; r++) {
                int m = m0 + mt*16 + quad*4 + r;
                C[(size_t)m*H_DIM + n0 + nt*16 + n] = acc[mt][nt][r];
            }
}

// ---------------------------------------------------------------------------
extern "C" void kernel_launch(void* const* d_in, const int* in_sizes, int n_in,
                              void* d_out, int out_size, void* d_ws, size_t ws_size,
                              hipStream_t stream)
{
    const float* Xh = (const float*)d_in[0];
    const float* Wq = (const float*)d_in[1];
    const float* Wk = (const float*)d_in[2];
    const float* Wv = (const float*)d_in[3];
    const float* Wo = (const float*)d_in[4];
    float* out = (float*)d_out;

    f16_t* Xf  = (f16_t*)d_ws;                  // XCNT
    f16_t* Wf  = Xf + XCNT;                     // 4*WCNT
    f16_t* Q16 = Wf + 4*(size_t)WCNT;           // XCNT
    f16_t* K16 = Q16 + XCNT;                    // XCNT
    f16_t* Vt  = K16 + XCNT;                    // XCNT
    f16_t* Of  = Vt + XCNT;                     // XCNT
    float4* accbuf = (float4*)(Of + XCNT);      // NUNITS*2*64 float4
    float*  lbuf   = (float*)(accbuf + (size_t)NUNITS*2*64);

    const int total4 = (XCNT + 4*WCNT)/4;
    cvt_f16<<<dim3((total4 + 255)/256), 256, 0, stream>>>(Xh, Wq, Wk, Wv, Wo, Xf, Wf);
    qkv_mfma<<<dim3(18, 128), 64, 0, stream>>>(Xf, Wf, Q16, K16, Vt);
    attn_part<<<dim3(NUNITS/4), 256, 0, stream>>>(Q16, K16, Vt, accbuf, lbuf);
    attn_red<<<dim3(NQUNITS/4), 256, 0, stream>>>(accbuf, lbuf, Of);
    out_mfma<<<dim3(6, 128), 64, 0, stream>>>(Of, Wf + 3*(size_t)WCNT, out);
}